// Round 9
// baseline (406.963 us; speedup 1.0000x reference)
//
#include <hip/hip_runtime.h>
#include <hip/hip_bf16.h>
#include <stdint.h>

typedef __hip_bfloat16 bf16;
typedef __bf16 bf16x8 __attribute__((ext_vector_type(8)));
typedef float f32x4 __attribute__((ext_vector_type(4)));

#define S_LEN 2048
#define EMB   2048
#define NH    16
#define HD    128

// async global->LDS, 16B per lane. LDS dest must be wave-uniform base + lane*16.
__device__ __forceinline__ void glds16(const void* g, void* l) {
  __builtin_amdgcn_global_load_lds(
      (__attribute__((address_space(1))) void*)g,
      (__attribute__((address_space(3))) void*)l,
      16, 0, 0);
}

// ---------------------------------------------------------------------------
// Kernel 0: fused f32 -> bf16 conversion of x, w_qkv, w_out (one launch).
// ---------------------------------------------------------------------------
__global__ __launch_bounds__(256) void cvt3_k(
    const float* __restrict__ xa, bf16* __restrict__ xo,
    const float* __restrict__ wa, bf16* __restrict__ wo1,
    const float* __restrict__ oa, bf16* __restrict__ oo)
{
  const int bid = blockIdx.x;
  const float* src; bf16* dst; int i;
  if (bid < 8192)       { src = xa; dst = xo;  i = bid * 256 + threadIdx.x; }
  else if (bid < 20480) { src = wa; dst = wo1; i = (bid - 8192) * 256 + threadIdx.x; }
  else                  { src = oa; dst = oo;  i = (bid - 20480) * 256 + threadIdx.x; }
  const float4 v = ((const float4*)src)[i];
  bf16 tmp[4];
  tmp[0] = __float2bfloat16(v.x);
  tmp[1] = __float2bfloat16(v.y);
  tmp[2] = __float2bfloat16(v.z);
  tmp[3] = __float2bfloat16(v.w);
  ((uint2*)dst)[i] = *(const uint2*)tmp;
}

// ===========================================================================
// GEMM geometry (both GEMMs): 128x128 tile, BK=64, 256 thr/4 waves,
// per-wave 64x64. LDS 32KB. R7-measured: qkv 139.7us, conflicts 0.
// T2 XOR swizzle: 16B-chunk ^= (row&7); inverse-swizzled global source +
// linear glds dest + swizzled ds_read (both-sides involution).
// ===========================================================================

// ---------------------------------------------------------------------------
// Kernel 1: qkv = x @ w_qkv^T + b_qkv  (R7-measured version — FROZEN).
// ---------------------------------------------------------------------------
__global__ __launch_bounds__(256) void gemm_qkv_k(
    const bf16* __restrict__ x, const bf16* __restrict__ w,
    const float* __restrict__ bias,
    bf16* __restrict__ q_ws, bf16* __restrict__ k_ws, bf16* __restrict__ v_t)
{
  __shared__ alignas(16) bf16 sA[128 * 64];
  __shared__ alignas(16) bf16 sW[128 * 64];
  const int n0 = blockIdx.x * 128;
  const int m0 = blockIdx.y * 128;

  const int t    = threadIdx.x;
  const int lane = t & 63, quad = lane >> 4, l15 = lane & 15;
  const int wave = t >> 6;
  const int wm0  = (wave >> 1) * 64, wn0 = (wave & 1) * 64;

  f32x4 acc[4][4];
#pragma unroll
  for (int mi = 0; mi < 4; mi++)
#pragma unroll
    for (int ni = 0; ni < 4; ni++)
#pragma unroll
      for (int r = 0; r < 4; r++) acc[mi][ni][r] = 0.f;

  for (int k0 = 0; k0 < EMB; k0 += 64) {
#pragma unroll
    for (int i = 0; i < 4; i++) {
      const int lin = i * 256 + t;              // 0..1023
      const int row = lin >> 3;                 // 0..127
      const int c16 = lin & 7;                  // 16B chunk in row
      const int col = (c16 ^ (row & 7)) * 8;    // inverse-swizzled source col
      glds16(x + (size_t)(m0 + row) * EMB + k0 + col, sA + (size_t)lin * 8);
      glds16(w + (size_t)(n0 + row) * EMB + k0 + col, sW + (size_t)lin * 8);
    }
    __syncthreads();
    bf16x8 af[4][2], wf[4][2];
#pragma unroll
    for (int mi = 0; mi < 4; mi++) {
      const int r = wm0 + mi * 16 + l15;
#pragma unroll
      for (int kk = 0; kk < 2; kk++) {
        const int ch = (kk * 4 + quad) ^ (r & 7);
        af[mi][kk] = *(const bf16x8*)(sA + r * 64 + ch * 8);
      }
    }
#pragma unroll
    for (int ni = 0; ni < 4; ni++) {
      const int r = wn0 + ni * 16 + l15;
#pragma unroll
      for (int kk = 0; kk < 2; kk++) {
        const int ch = (kk * 4 + quad) ^ (r & 7);
        wf[ni][kk] = *(const bf16x8*)(sW + r * 64 + ch * 8);
      }
    }
#pragma unroll
    for (int mi = 0; mi < 4; mi++)
#pragma unroll
      for (int ni = 0; ni < 4; ni++)
#pragma unroll
        for (int kk = 0; kk < 2; kk++)
          acc[mi][ni] = __builtin_amdgcn_mfma_f32_16x16x32_bf16(af[mi][kk], wf[ni][kk], acc[mi][ni], 0, 0, 0);
    __syncthreads();
  }

  const int which = n0 >> 11;                 // 0=q,1=k,2=v (whole block same)
  bf16* dst = (which == 0) ? q_ws : ((which == 1) ? k_ws : v_t);

#pragma unroll
  for (int mi = 0; mi < 4; mi++) {
#pragma unroll
    for (int ni = 0; ni < 4; ni++) {
      const int n_g = n0 + wn0 + ni * 16 + l15;
      const int h   = (n_g >> 7) & 15;
      const int d   = n_g & 127;
      const float bv = bias[n_g];
#pragma unroll
      for (int r = 0; r < 4; r++) {
        const int m_g = m0 + wm0 + mi * 16 + quad * 4 + r;
        const int b   = m_g >> 11;
        const int s   = m_g & 2047;
        const size_t idx = (which == 2)
            ? ((size_t)(b * NH + h) * HD + d) * S_LEN + s      // V: [b,h,d,s]
            : ((size_t)(b * NH + h) * S_LEN + s) * HD + d;     // Q/K: [b,h,s,d]
        dst[idx] = __float2bfloat16(acc[mi][ni][r] + bv);
      }
    }
  }
}

// ---------------------------------------------------------------------------
// Kernel 2: causal flash attention. R8 structure (8 waves x 16 Q-rows,
// heavy+light Q-tile pair per block, grid 256, XOR-swizzled K/V LDS,
// exp2 softmax diet) with KVBLK=128: half the iterations (17 vs 34), half
// the barriers, 64 MFMA/wave per iter. P buffer [16][72] time-shared across
// the two 64-col halves (per-wave private; in-wave DS ordering suffices).
// LDS 146KB -> 1 block/CU (2 waves/SIMD, same as R8).
// ---------------------------------------------------------------------------
__global__ __launch_bounds__(512, 1) void attn_k(
    const bf16* __restrict__ q_ws, const bf16* __restrict__ k_ws,
    const bf16* __restrict__ v_t, bf16* __restrict__ attn_out)
{
  __shared__ alignas(16) bf16 smK[2][128 * 128];   // [c4][row128][32] chunked
  __shared__ alignas(16) bf16 smV[2][128 * 128];   // [c4][d128][32] chunked
  __shared__ alignas(16) bf16 smP[8][16 * 72];

  const int t    = threadIdx.x;
  const int lane = t & 63, quad = lane >> 4, l15 = lane & 15;
  const int w    = t >> 6;                  // 0..7
  const int bh   = blockIdx.x >> 3;
  const int pr   = blockIdx.x & 7;
  const size_t hb = (size_t)bh * (S_LEN * HD);
  bf16* myP = smP[w];
  const float C = 0.12751745f;   // (1/sqrt(128)) * log2(e)
  const int sw = quad ^ ((l15 >> 1) & 3);   // swizzled 16B-slot for K/V reads

  // stage K tile: [4 c][128 kv][32 d], 4 glds/thread
  auto stageK = [&](int kv0, bf16* dst) {
#pragma unroll
    for (int i = 0; i < 4; i++) {
      const int lin = i * 512 + t;           // 0..2047
      const int cc  = lin >> 9;              // d-chunk 0..3
      const int row = (lin >> 2) & 127;      // kv index
      const int sl  = (lin & 3) ^ ((row >> 1) & 3);   // inverse-swizzled source
      glds16(k_ws + hb + (size_t)(kv0 + row) * HD + cc * 32 + sl * 8,
             dst + (size_t)lin * 8);
    }
  };
  // stage V tile: [4 c][128 d][32 s], 4 glds/thread
  auto stageV = [&](int kv0, bf16* dst) {
#pragma unroll
    for (int i = 0; i < 4; i++) {
      const int lin = i * 512 + t;
      const int cc  = lin >> 9;              // s-chunk 0..3
      const int row = (lin >> 2) & 127;      // d index
      const int sl  = (lin & 3) ^ ((row >> 1) & 3);
      glds16(v_t + hb + (size_t)row * S_LEN + kv0 + cc * 32 + sl * 8,
             dst + (size_t)lin * 8);
    }
  };

  for (int ph = 0; ph < 2; ++ph) {
    const int qt     = ph ? pr : (15 - pr);   // heavy tile first
    const int qbase  = qt * 128;
    const int ntiles = qt + 1;                // KV tiles of 128
    const int wrow0  = qbase + w * 16;        // this wave's 16 Q rows
    const int wrow_hi = wrow0 + 15;

    // Q fragments straight from global (registers; no LDS staging)
    bf16x8 qf[4];
#pragma unroll
    for (int ks = 0; ks < 4; ++ks)
      qf[ks] = *(const bf16x8*)(q_ws + hb + (size_t)(wrow0 + l15) * HD + ks * 32 + quad * 8);

    f32x4 o_acc[8];
    float m_st[4], l_st[4];
#pragma unroll
    for (int dt = 0; dt < 8; ++dt)
#pragma unroll
      for (int r = 0; r < 4; ++r) o_acc[dt][r] = 0.f;
#pragma unroll
    for (int r = 0; r < 4; ++r) { m_st[r] = -1e30f; l_st[r] = 0.f; }

    stageK(0, smK[0]);
    stageV(0, smV[0]);

    for (int tile = 0; tile < ntiles; ++tile) {
      const int cur = tile & 1;
      if (tile + 1 < ntiles) {
        const int kv1 = (tile + 1) * 128;
        stageK(kv1, smK[cur ^ 1]);
        stageV(kv1, smV[cur ^ 1]);
        asm volatile("s_waitcnt vmcnt(8)" ::: "memory");   // keep prefetch in flight
      } else {
        asm volatile("s_waitcnt vmcnt(0)" ::: "memory");
      }
      __builtin_amdgcn_s_barrier();

      const int kv0 = tile * 128;
      if (kv0 <= wrow_hi) {
        // ---- QK^T (16 q-rows x 128 kv) ----
        f32x4 sc[8];
#pragma unroll
        for (int ni = 0; ni < 8; ni++)
#pragma unroll
          for (int r = 0; r < 4; r++) sc[ni][r] = 0.f;
        const bf16* kb = smK[cur];
#pragma unroll
        for (int ks = 0; ks < 4; ++ks) {
#pragma unroll
          for (int ni = 0; ni < 8; ++ni) {
            const bf16x8 kf = *(const bf16x8*)(kb + (ks * 128 + ni * 16 + l15) * 32 + sw * 8);
            sc[ni] = __builtin_amdgcn_mfma_f32_16x16x32_bf16(qf[ks], kf, sc[ni], 0, 0, 0);
          }
        }

        // ---- per 64-col half: online softmax + PV (P buffer time-shared) --
        const bf16* vb = smV[cur];
#pragma unroll
        for (int hf = 0; hf < 2; ++hf) {
          const int hbase = kv0 + hf * 64;
          if (hbase > wrow_hi) continue;            // half fully masked
          const bool needmask = (hbase + 63 > wrow0);   // wave-uniform
#pragma unroll
          for (int r = 0; r < 4; ++r) {
            const int qg = wrow0 + quad * 4 + r;
            float xs[4];
            float vmax = -1e30f;
            if (needmask) {
#pragma unroll
              for (int ni = 0; ni < 4; ++ni) {
                const int kg = hbase + ni * 16 + l15;
                float xv = sc[hf * 4 + ni][r] * C;
                xv = (kg > qg) ? -1e30f : xv;
                xs[ni] = xv;
                vmax = fmaxf(vmax, xv);
              }
            } else {
#pragma unroll
              for (int ni = 0; ni < 4; ++ni) {
                const float xv = sc[hf * 4 + ni][r] * C;
                xs[ni] = xv;
                vmax = fmaxf(vmax, xv);
              }
            }
            float m_old = m_st[r];
            if (!__all(vmax <= m_old + 8.f)) {        // rare after first half
#pragma unroll
              for (int off = 1; off < 16; off <<= 1)
                vmax = fmaxf(vmax, __shfl_xor(vmax, off, 64));
              const float mnew  = fmaxf(m_old, vmax);
              const float alpha = __builtin_amdgcn_exp2f(m_old - mnew);
              l_st[r] *= alpha;
#pragma unroll
              for (int dt = 0; dt < 8; ++dt) o_acc[dt][r] *= alpha;
              m_st[r] = mnew;
              m_old = mnew;
            }
            float ps = 0.f;
#pragma unroll
            for (int ni = 0; ni < 4; ++ni) {
              const float p = __builtin_amdgcn_exp2f(xs[ni] - m_old);
              ps += p;
              myP[(quad * 4 + r) * 72 + ni * 16 + l15] = __float2bfloat16(p);
            }
            l_st[r] += ps;   // per-lane partial; reduced once in epilogue
          }

          // ---- P @ V for this half (per-wave P; in-wave DS order only) ----
#pragma unroll
          for (int ks2 = 0; ks2 < 2; ++ks2) {
            const bf16x8 pa = *(const bf16x8*)(myP + l15 * 72 + ks2 * 32 + quad * 8);
#pragma unroll
            for (int dt = 0; dt < 8; ++dt) {
              const bf16x8 vf = *(const bf16x8*)(vb + ((hf * 2 + ks2) * 128 + dt * 16 + l15) * 32 + sw * 8);
              o_acc[dt] = __builtin_amdgcn_mfma_f32_16x16x32_bf16(pa, vf, o_acc[dt], 0, 0, 0);
            }
          }
        }
      }
      __builtin_amdgcn_s_barrier();   // all reads of buf[cur] done before reuse
    }

    // ---- epilogue: reduce l across the 16-lane row groups, write O/l ----
#pragma unroll
    for (int r = 0; r < 4; ++r) {
      float l = l_st[r];
#pragma unroll
      for (int off = 1; off < 16; off <<= 1) l += __shfl_xor(l, off, 64);
      const float rl = 1.f / l;
      const int sg = wrow0 + quad * 4 + r;
      const size_t rowoff = hb + (size_t)sg * HD;
#pragma unroll
      for (int dt = 0; dt < 8; ++dt)
        attn_out[rowoff + dt * 16 + l15] = __float2bfloat16(o_acc[dt][r] * rl);
    }
  }
}

// ---------------------------------------------------------------------------
// Kernel 3: out = attn @ w_out^T + b_out  (R7-measured version — FROZEN).
// attn stored [b,h,s,d] (logical A[m=b*2048+s][k=h*128+d]). OUTPUT FLOAT32.
// ---------------------------------------------------------------------------
__global__ __launch_bounds__(256) void gemm_out_k(
    const bf16* __restrict__ attn, const bf16* __restrict__ w,
    const float* __restrict__ bias, float* __restrict__ out)
{
  __shared__ alignas(16) bf16 sA[128 * 64];
  __shared__ alignas(16) bf16 sW[128 * 64];
  const int n0 = blockIdx.x * 128;
  const int m0 = blockIdx.y * 128;

  const int t    = threadIdx.x;
  const int lane = t & 63, quad = lane >> 4, l15 = lane & 15;
  const int wave = t >> 6;
  const int wm0  = (wave >> 1) * 64, wn0 = (wave & 1) * 64;

  f32x4 acc[4][4];
#pragma unroll
  for (int mi = 0; mi < 4; mi++)
#pragma unroll
    for (int ni = 0; ni < 4; ni++)
#pragma unroll
      for (int r = 0; r < 4; r++) acc[mi][ni][r] = 0.f;

  for (int k0 = 0; k0 < EMB; k0 += 64) {
    const int h  = k0 >> 7;          // 64-wide K range never crosses a head
    const int d0 = k0 & 127;
#pragma unroll
    for (int i = 0; i < 4; i++) {
      const int lin = i * 256 + t;              // 0..1023
      const int row = lin >> 3;                 // 0..127
      const int c16 = lin & 7;
      const int col = (c16 ^ (row & 7)) * 8;    // inverse-swizzled source col
      const int m   = m0 + row;
      const int b   = m >> 11;
      const int s   = m & 2047;
      glds16(attn + ((size_t)(b * NH + h) * S_LEN + s) * HD + d0 + col,
             sA + (size_t)lin * 8);
      glds16(w + (size_t)(n0 + row) * EMB + k0 + col, sW + (size_t)lin * 8);
    }
    __syncthreads();
    bf16x8 af[4][2], wf[4][2];
#pragma unroll
    for (int mi = 0; mi < 4; mi++) {
      const int r = wm0 + mi * 16 + l15;
#pragma unroll
      for (int kk = 0; kk < 2; kk++) {
        const int ch = (kk * 4 + quad) ^ (r & 7);
        af[mi][kk] = *(const bf16x8*)(sA + r * 64 + ch * 8);
      }
    }
#pragma unroll
    for (int ni = 0; ni < 4; ni++) {
      const int r = wn0 + ni * 16 + l15;
#pragma unroll
      for (int kk = 0; kk < 2; kk++) {
        const int ch = (kk * 4 + quad) ^ (r & 7);
        wf[ni][kk] = *(const bf16x8*)(sW + r * 64 + ch * 8);
      }
    }
#pragma unroll
    for (int mi = 0; mi < 4; mi++)
#pragma unroll
      for (int ni = 0; ni < 4; ni++)
#pragma unroll
        for (int kk = 0; kk < 2; kk++)
          acc[mi][ni] = __builtin_amdgcn_mfma_f32_16x16x32_bf16(af[mi][kk], wf[ni][kk], acc[mi][ni], 0, 0, 0);
    __syncthreads();
  }

#pragma unroll
  for (int mi = 0; mi < 4; mi++) {
#pragma unroll
    for (int ni = 0; ni < 4; ni++) {
      const int n_g = n0 + wn0 + ni * 16 + l15;
      const float bv = bias[n_g];
#pragma unroll
      for (int r = 0; r < 4; r++) {
        const int m_g = m0 + wm0 + mi * 16 + quad * 4 + r;
        out[(size_t)m_g * EMB + n_g] = acc[mi][ni][r] + bv;   // f32 store
      }
    }
  }
}

// ---------------------------------------------------------------------------
// Workspace layout (96 MiB):
//   [ 0,16)  MiB: xb  bf16 (x converted) -> attn output [b,h,s,d] after QKV
//   [16,40)  MiB: wqb bf16 (w_qkv converted)
//   [40,48)  MiB: wob bf16 (w_out converted)
//   [48,64)  MiB: q [b,h,s,d]
//   [64,80)  MiB: k [b,h,s,d]
//   [80,96)  MiB: v_t [b,h,d,s] (written directly transposed by gemm_qkv_k)
// ---------------------------------------------------------------------------
extern "C" void kernel_launch(void* const* d_in, const int* in_sizes, int n_in,
                              void* d_out, int out_size, void* d_ws, size_t ws_size,
                              hipStream_t stream)
{
  const float* x_f     = (const float*)d_in[0];
  // d_in[1] = attn_mask (causal triu) — known analytically, ignored.
  const float* w_qkv_f = (const float*)d_in[2];
  const float* b_qkv   = (const float*)d_in[3];
  const float* w_out_f = (const float*)d_in[4];
  const float* b_out   = (const float*)d_in[5];
  float* out = (float*)d_out;   // reference output dtype is float32

  char* ws = (char*)d_ws;
  const size_t MB = 1024 * 1024;
  bf16* xb   = (bf16*)(ws);
  bf16* wqb  = (bf16*)(ws + 16 * MB);
  bf16* wob  = (bf16*)(ws + 40 * MB);
  bf16* q_ws = (bf16*)(ws + 48 * MB);
  bf16* k_ws = (bf16*)(ws + 64 * MB);
  bf16* v_t  = (bf16*)(ws + 80 * MB);
  bf16* attn = xb;   // xb dead after gemm_qkv_k; distinct from q_ws (no alias)

  cvt3_k<<<dim3(24576), 256, 0, stream>>>(x_f, xb, w_qkv_f, wqb, w_out_f, wob);

  gemm_qkv_k<<<dim3(48, 32), 256, 0, stream>>>(xb, wqb, b_qkv, q_ws, k_ws, v_t);
  attn_k<<<dim3(256), 512, 0, stream>>>(q_ws, k_ws, v_t, attn);
  gemm_out_k<<<dim3(16, 32), 256, 0, stream>>>(attn, wob, b_out, out);
}

// Round 10
// 402.691 us; speedup vs baseline: 1.0106x; 1.0106x over previous
//
#include <hip/hip_runtime.h>
#include <hip/hip_bf16.h>
#include <stdint.h>

typedef __hip_bfloat16 bf16;
typedef __bf16 bf16x8 __attribute__((ext_vector_type(8)));
typedef float f32x4 __attribute__((ext_vector_type(4)));

#define S_LEN 2048
#define EMB   2048
#define NH    16
#define HD    128

// async global->LDS, 16B per lane. LDS dest must be wave-uniform base + lane*16.
__device__ __forceinline__ void glds16(const void* g, void* l) {
  __builtin_amdgcn_global_load_lds(
      (__attribute__((address_space(1))) void*)g,
      (__attribute__((address_space(3))) void*)l,
      16, 0, 0);
}

// ---------------------------------------------------------------------------
// Kernel 0: fused f32 -> bf16 conversion of x, w_qkv, w_out (one launch).
// ---------------------------------------------------------------------------
__global__ __launch_bounds__(256) void cvt3_k(
    const float* __restrict__ xa, bf16* __restrict__ xo,
    const float* __restrict__ wa, bf16* __restrict__ wo1,
    const float* __restrict__ oa, bf16* __restrict__ oo)
{
  const int bid = blockIdx.x;
  const float* src; bf16* dst; int i;
  if (bid < 8192)       { src = xa; dst = xo;  i = bid * 256 + threadIdx.x; }
  else if (bid < 20480) { src = wa; dst = wo1; i = (bid - 8192) * 256 + threadIdx.x; }
  else                  { src = oa; dst = oo;  i = (bid - 20480) * 256 + threadIdx.x; }
  const float4 v = ((const float4*)src)[i];
  bf16 tmp[4];
  tmp[0] = __float2bfloat16(v.x);
  tmp[1] = __float2bfloat16(v.y);
  tmp[2] = __float2bfloat16(v.z);
  tmp[3] = __float2bfloat16(v.w);
  ((uint2*)dst)[i] = *(const uint2*)tmp;
}

// ===========================================================================
// GEMM geometry (both GEMMs): 128x128 tile, BK=64, 256 thr/4 waves,
// per-wave 64x64. T2 XOR swizzle (16B-chunk ^= row&7, both-sides involution).
// NEW this round — T3 "minimum 2-phase" schedule (m248v2 recipe):
//   prologue: STAGE(0, buf0); vmcnt(0); barrier;
//   for kt:   STAGE(kt+1, buf[cur^1]);      // issued FIRST -> covered by MFMA
//             ds_read frags(buf[cur]); 32 MFMA;
//             vmcnt(0); s_barrier;          // ONE barrier per K-tile
//             cur ^= 1;
// vs R7: two barriers/tile and a zero-cover drain right after issue.
// Race-audit: stage targets the buffer NOT read this iter; frag ds_reads of
// buf[cur] complete before MFMA which precedes the barrier, so next iter's
// stage into buf[cur] cannot overwrite live data; end-of-iter vmcnt(0)+
// barrier collectivizes landing of buf[cur^1] before any wave reads it.
// LDS double-buffer 64KB -> still 2 blocks/CU (TLP preserved).
// ===========================================================================

// ---------------------------------------------------------------------------
// Kernel 1: qkv = x @ w_qkv^T + b_qkv. Q,K scattered into [b,h,s,d];
// V written TRANSPOSED into v_t [b,h,d,s].
// ---------------------------------------------------------------------------
__global__ __launch_bounds__(256) void gemm_qkv_k(
    const bf16* __restrict__ x, const bf16* __restrict__ w,
    const float* __restrict__ bias,
    bf16* __restrict__ q_ws, bf16* __restrict__ k_ws, bf16* __restrict__ v_t)
{
  __shared__ alignas(16) bf16 sA[2][128 * 64];
  __shared__ alignas(16) bf16 sW[2][128 * 64];
  const int n0 = blockIdx.x * 128;
  const int m0 = blockIdx.y * 128;

  const int t    = threadIdx.x;
  const int lane = t & 63, quad = lane >> 4, l15 = lane & 15;
  const int wave = t >> 6;
  const int wm0  = (wave >> 1) * 64, wn0 = (wave & 1) * 64;

  auto stage = [&](int k0, int buf) {
#pragma unroll
    for (int i = 0; i < 4; i++) {
      const int lin = i * 256 + t;              // 0..1023
      const int row = lin >> 3;                 // 0..127
      const int c16 = lin & 7;                  // 16B chunk in row
      const int col = (c16 ^ (row & 7)) * 8;    // inverse-swizzled source col
      glds16(x + (size_t)(m0 + row) * EMB + k0 + col, sA[buf] + (size_t)lin * 8);
      glds16(w + (size_t)(n0 + row) * EMB + k0 + col, sW[buf] + (size_t)lin * 8);
    }
  };

  f32x4 acc[4][4];
#pragma unroll
  for (int mi = 0; mi < 4; mi++)
#pragma unroll
    for (int ni = 0; ni < 4; ni++)
#pragma unroll
      for (int r = 0; r < 4; r++) acc[mi][ni][r] = 0.f;

  stage(0, 0);
  asm volatile("s_waitcnt vmcnt(0)" ::: "memory");
  __builtin_amdgcn_s_barrier();

  int cur = 0;
  for (int kt = 0; kt < 32; ++kt) {
    if (kt + 1 < 32) stage((kt + 1) * 64, cur ^ 1);   // covered by this iter's MFMA

    bf16x8 af[4][2], wf[4][2];
#pragma unroll
    for (int mi = 0; mi < 4; mi++) {
      const int r = wm0 + mi * 16 + l15;
#pragma unroll
      for (int kk = 0; kk < 2; kk++) {
        const int ch = (kk * 4 + quad) ^ (r & 7);
        af[mi][kk] = *(const bf16x8*)(sA[cur] + r * 64 + ch * 8);
      }
    }
#pragma unroll
    for (int ni = 0; ni < 4; ni++) {
      const int r = wn0 + ni * 16 + l15;
#pragma unroll
      for (int kk = 0; kk < 2; kk++) {
        const int ch = (kk * 4 + quad) ^ (r & 7);
        wf[ni][kk] = *(const bf16x8*)(sW[cur] + r * 64 + ch * 8);
      }
    }
#pragma unroll
    for (int mi = 0; mi < 4; mi++)
#pragma unroll
      for (int ni = 0; ni < 4; ni++)
#pragma unroll
        for (int kk = 0; kk < 2; kk++)
          acc[mi][ni] = __builtin_amdgcn_mfma_f32_16x16x32_bf16(af[mi][kk], wf[ni][kk], acc[mi][ni], 0, 0, 0);

    if (kt + 1 < 32) {
      asm volatile("s_waitcnt vmcnt(0)" ::: "memory");  // stage(kt+1) landed
      __builtin_amdgcn_s_barrier();                     // one barrier per tile
    }
    cur ^= 1;
  }

  const int which = n0 >> 11;                 // 0=q,1=k,2=v (whole block same)
  bf16* dst = (which == 0) ? q_ws : ((which == 1) ? k_ws : v_t);

#pragma unroll
  for (int mi = 0; mi < 4; mi++) {
#pragma unroll
    for (int ni = 0; ni < 4; ni++) {
      const int n_g = n0 + wn0 + ni * 16 + l15;
      const int h   = (n_g >> 7) & 15;
      const int d   = n_g & 127;
      const float bv = bias[n_g];
#pragma unroll
      for (int r = 0; r < 4; r++) {
        const int m_g = m0 + wm0 + mi * 16 + quad * 4 + r;
        const int b   = m_g >> 11;
        const int s   = m_g & 2047;
        const size_t idx = (which == 2)
            ? ((size_t)(b * NH + h) * HD + d) * S_LEN + s      // V: [b,h,d,s]
            : ((size_t)(b * NH + h) * S_LEN + s) * HD + d;     // Q/K: [b,h,s,d]
        dst[idx] = __float2bfloat16(acc[mi][ni][r] + bv);
      }
    }
  }
}

// ---------------------------------------------------------------------------
// Kernel 2: causal flash attention — EXACT R8 version (measured best,
// 403.9 us total). 8 waves x 16 Q-rows, heavy+light pair per block, grid
// 256, K/V dbuf + counted vmcnt, XOR-swizzled LDS, exp2 softmax diet.
// ---------------------------------------------------------------------------
__global__ __launch_bounds__(512, 2) void attn_k(
    const bf16* __restrict__ q_ws, const bf16* __restrict__ k_ws,
    const bf16* __restrict__ v_t, bf16* __restrict__ attn_out)
{
  __shared__ alignas(16) bf16 smK[2][8192];
  __shared__ alignas(16) bf16 smV[2][8192];
  __shared__ alignas(16) bf16 smP[8][16 * 72];

  const int t    = threadIdx.x;
  const int lane = t & 63, quad = lane >> 4, l15 = lane & 15;
  const int w    = t >> 6;                  // 0..7
  const int bh   = blockIdx.x >> 3;
  const int pr   = blockIdx.x & 7;
  const size_t hb = (size_t)bh * (S_LEN * HD);
  bf16* myP = smP[w];
  const float C = 0.12751745f;   // (1/sqrt(128)) * log2(e)
  const int sw = quad ^ ((l15 >> 1) & 3);   // swizzled 16B-slot for K/V reads

  auto stageK = [&](int kv0, bf16* dst) {
#pragma unroll
    for (int i = 0; i < 2; i++) {
      const int lin = i * 512 + t;           // 0..1023
      const int cc  = lin >> 8;              // k-chunk 0..3
      const int row = (lin >> 2) & 63;
      const int sl  = (lin & 3) ^ ((row >> 1) & 3);   // inverse-swizzled source
      glds16(k_ws + hb + (size_t)(kv0 + row) * HD + cc * 32 + sl * 8,
             dst + (size_t)lin * 8);
    }
  };
  auto stageV = [&](int kv0, bf16* dst) {
#pragma unroll
    for (int i = 0; i < 2; i++) {
      const int lin = i * 512 + t;
      const int cc  = lin >> 9;              // s-chunk 0..1
      const int row = (lin >> 2) & 127;      // d index
      const int sl  = (lin & 3) ^ ((row >> 1) & 3);
      glds16(v_t + hb + (size_t)row * S_LEN + kv0 + cc * 32 + sl * 8,
             dst + (size_t)lin * 8);
    }
  };

  for (int ph = 0; ph < 2; ++ph) {
    const int qt     = ph ? pr : (15 - pr);   // heavy tile first
    const int qbase  = qt * 128;
    const int ntiles = 2 * qt + 2;
    const int wrow0  = qbase + w * 16;        // this wave's 16 Q rows
    const int wrow_hi = wrow0 + 15;

    // Q fragments straight from global (registers; no LDS staging)
    bf16x8 qf[4];
#pragma unroll
    for (int ks = 0; ks < 4; ++ks)
      qf[ks] = *(const bf16x8*)(q_ws + hb + (size_t)(wrow0 + l15) * HD + ks * 32 + quad * 8);

    f32x4 o_acc[8];
    float m_st[4], l_st[4];
#pragma unroll
    for (int dt = 0; dt < 8; ++dt)
#pragma unroll
      for (int r = 0; r < 4; ++r) o_acc[dt][r] = 0.f;
#pragma unroll
    for (int r = 0; r < 4; ++r) { m_st[r] = -1e30f; l_st[r] = 0.f; }

    stageK(0, smK[0]);
    stageV(0, smV[0]);

    for (int tile = 0; tile < ntiles; ++tile) {
      const int cur = tile & 1;
      if (tile + 1 < ntiles) {
        const int kv1 = (tile + 1) * 64;
        stageK(kv1, smK[cur ^ 1]);
        stageV(kv1, smV[cur ^ 1]);
        asm volatile("s_waitcnt vmcnt(4)" ::: "memory");   // keep prefetch in flight
      } else {
        asm volatile("s_waitcnt vmcnt(0)" ::: "memory");
      }
      __builtin_amdgcn_s_barrier();

      const int kv0 = tile * 64;
      if (kv0 <= wrow_hi) {
        // ---- QK^T (16 q-rows x 64 kv) ----
        f32x4 sc[4];
#pragma unroll
        for (int ni = 0; ni < 4; ni++)
#pragma unroll
          for (int r = 0; r < 4; r++) sc[ni][r] = 0.f;
        const bf16* kb = smK[cur];
#pragma unroll
        for (int ks = 0; ks < 4; ++ks) {
          bf16x8 kf[4];
#pragma unroll
          for (int ni = 0; ni < 4; ++ni)
            kf[ni] = *(const bf16x8*)(kb + (ks * 64 + ni * 16 + l15) * 32 + sw * 8);
#pragma unroll
          for (int ni = 0; ni < 4; ++ni)
            sc[ni] = __builtin_amdgcn_mfma_f32_16x16x32_bf16(qf[ks], kf[ni], sc[ni], 0, 0, 0);
        }

        // ---- online softmax (exp2 domain, defer-max, per-lane l) ----
        const bool needmask = (kv0 + 63 > wrow0);   // wave-uniform
#pragma unroll
        for (int r = 0; r < 4; ++r) {
          const int qg = wrow0 + quad * 4 + r;
          float xs[4];
          float vmax = -1e30f;
          if (needmask) {
#pragma unroll
            for (int ni = 0; ni < 4; ++ni) {
              const int kg = kv0 + ni * 16 + l15;
              float xv = sc[ni][r] * C;
              xv = (kg > qg) ? -1e30f : xv;
              xs[ni] = xv;
              vmax = fmaxf(vmax, xv);
            }
          } else {
#pragma unroll
            for (int ni = 0; ni < 4; ++ni) {
              const float xv = sc[ni][r] * C;
              xs[ni] = xv;
              vmax = fmaxf(vmax, xv);
            }
          }
          float m_old = m_st[r];
          if (!__all(vmax <= m_old + 8.f)) {        // rare after tile 0
#pragma unroll
            for (int off = 1; off < 16; off <<= 1)
              vmax = fmaxf(vmax, __shfl_xor(vmax, off, 64));
            const float mnew  = fmaxf(m_old, vmax);
            const float alpha = __builtin_amdgcn_exp2f(m_old - mnew);
            l_st[r] *= alpha;
#pragma unroll
            for (int dt = 0; dt < 8; ++dt) o_acc[dt][r] *= alpha;
            m_st[r] = mnew;
            m_old = mnew;
          }
          float ps = 0.f;
#pragma unroll
          for (int ni = 0; ni < 4; ++ni) {
            const float p = __builtin_amdgcn_exp2f(xs[ni] - m_old);
            ps += p;
            myP[(quad * 4 + r) * 72 + ni * 16 + l15] = __float2bfloat16(p);
          }
          l_st[r] += ps;   // per-lane partial; reduced once in epilogue
        }

        // ---- P @ V (per-wave P, no barrier needed) ----
        const bf16* vb = smV[cur];
#pragma unroll
        for (int ks2 = 0; ks2 < 2; ++ks2) {
          const bf16x8 pa = *(const bf16x8*)(myP + l15 * 72 + ks2 * 32 + quad * 8);
#pragma unroll
          for (int dt = 0; dt < 8; ++dt) {
            const bf16x8 vf = *(const bf16x8*)(vb + (ks2 * 128 + dt * 16 + l15) * 32 + sw * 8);
            o_acc[dt] = __builtin_amdgcn_mfma_f32_16x16x32_bf16(pa, vf, o_acc[dt], 0, 0, 0);
          }
        }
      }
      __builtin_amdgcn_s_barrier();   // all reads of buf[cur] done before reuse
    }

    // ---- epilogue: reduce l across the 16-lane row groups, write O/l ----
#pragma unroll
    for (int r = 0; r < 4; ++r) {
      float l = l_st[r];
#pragma unroll
      for (int off = 1; off < 16; off <<= 1) l += __shfl_xor(l, off, 64);
      const float rl = 1.f / l;
      const int sg = wrow0 + quad * 4 + r;
      const size_t rowoff = hb + (size_t)sg * HD;
#pragma unroll
      for (int dt = 0; dt < 8; ++dt)
        attn_out[rowoff + dt * 16 + l15] = __float2bfloat16(o_acc[dt][r] * rl);
    }
  }
}

// ---------------------------------------------------------------------------
// Kernel 3: out = attn @ w_out^T + b_out, attn stored [b,h,s,d]
// (logical A[m=b*2048+s][k=h*128+d]). OUTPUT FLOAT32.
// Same minimum-2-phase schedule as gemm_qkv_k.
// ---------------------------------------------------------------------------
__global__ __launch_bounds__(256) void gemm_out_k(
    const bf16* __restrict__ attn, const bf16* __restrict__ w,
    const float* __restrict__ bias, float* __restrict__ out)
{
  __shared__ alignas(16) bf16 sA[2][128 * 64];
  __shared__ alignas(16) bf16 sW[2][128 * 64];
  const int n0 = blockIdx.x * 128;
  const int m0 = blockIdx.y * 128;

  const int t    = threadIdx.x;
  const int lane = t & 63, quad = lane >> 4, l15 = lane & 15;
  const int wave = t >> 6;
  const int wm0  = (wave >> 1) * 64, wn0 = (wave & 1) * 64;

  auto stage = [&](int k0, int buf) {
    const int h  = k0 >> 7;          // 64-wide K range never crosses a head
    const int d0 = k0 & 127;
#pragma unroll
    for (int i = 0; i < 4; i++) {
      const int lin = i * 256 + t;              // 0..1023
      const int row = lin >> 3;                 // 0..127
      const int c16 = lin & 7;
      const int col = (c16 ^ (row & 7)) * 8;    // inverse-swizzled source col
      const int m   = m0 + row;
      const int b   = m >> 11;
      const int s   = m & 2047;
      glds16(attn + ((size_t)(b * NH + h) * S_LEN + s) * HD + d0 + col,
             sA[buf] + (size_t)lin * 8);
      glds16(w + (size_t)(n0 + row) * EMB + k0 + col, sW[buf] + (size_t)lin * 8);
    }
  };

  f32x4 acc[4][4];
#pragma unroll
  for (int mi = 0; mi < 4; mi++)
#pragma unroll
    for (int ni = 0; ni < 4; ni++)
#pragma unroll
      for (int r = 0; r < 4; r++) acc[mi][ni][r] = 0.f;

  stage(0, 0);
  asm volatile("s_waitcnt vmcnt(0)" ::: "memory");
  __builtin_amdgcn_s_barrier();

  int cur = 0;
  for (int kt = 0; kt < 32; ++kt) {
    if (kt + 1 < 32) stage((kt + 1) * 64, cur ^ 1);

    bf16x8 af[4][2], wf[4][2];
#pragma unroll
    for (int mi = 0; mi < 4; mi++) {
      const int r = wm0 + mi * 16 + l15;
#pragma unroll
      for (int kk = 0; kk < 2; kk++) {
        const int ch = (kk * 4 + quad) ^ (r & 7);
        af[mi][kk] = *(const bf16x8*)(sA[cur] + r * 64 + ch * 8);
      }
    }
#pragma unroll
    for (int ni = 0; ni < 4; ni++) {
      const int r = wn0 + ni * 16 + l15;
#pragma unroll
      for (int kk = 0; kk < 2; kk++) {
        const int ch = (kk * 4 + quad) ^ (r & 7);
        wf[ni][kk] = *(const bf16x8*)(sW[cur] + r * 64 + ch * 8);
      }
    }
#pragma unroll
    for (int mi = 0; mi < 4; mi++)
#pragma unroll
      for (int ni = 0; ni < 4; ni++)
#pragma unroll
        for (int kk = 0; kk < 2; kk++)
          acc[mi][ni] = __builtin_amdgcn_mfma_f32_16x16x32_bf16(af[mi][kk], wf[ni][kk], acc[mi][ni], 0, 0, 0);

    if (kt + 1 < 32) {
      asm volatile("s_waitcnt vmcnt(0)" ::: "memory");
      __builtin_amdgcn_s_barrier();
    }
    cur ^= 1;
  }

#pragma unroll
  for (int mi = 0; mi < 4; mi++) {
#pragma unroll
    for (int ni = 0; ni < 4; ni++) {
      const int n_g = n0 + wn0 + ni * 16 + l15;
      const float bv = bias[n_g];
#pragma unroll
      for (int r = 0; r < 4; r++) {
        const int m_g = m0 + wm0 + mi * 16 + quad * 4 + r;
        out[(size_t)m_g * EMB + n_g] = acc[mi][ni][r] + bv;   // f32 store
      }
    }
  }
}

// ---------------------------------------------------------------------------
// Workspace layout (96 MiB):
//   [ 0,16)  MiB: xb  bf16 (x converted) -> attn output [b,h,s,d] after QKV
//   [16,40)  MiB: wqb bf16 (w_qkv converted)
//   [40,48)  MiB: wob bf16 (w_out converted)
//   [48,64)  MiB: q [b,h,s,d]
//   [64,80)  MiB: k [b,h,s,d]
//   [80,96)  MiB: v_t [b,h,d,s] (written directly transposed by gemm_qkv_k)
// ---------------------------------------------------------------------------
extern "C" void kernel_launch(void* const* d_in, const int* in_sizes, int n_in,
                              void* d_out, int out_size, void* d_ws, size_t ws_size,
                              hipStream_t stream)
{
  const float* x_f     = (const float*)d_in[0];
  // d_in[1] = attn_mask (causal triu) — known analytically, ignored.
  const float* w_qkv_f = (const float*)d_in[2];
  const float* b_qkv   = (const float*)d_in[3];
  const float* w_out_f = (const float*)d_in[4];
  const float* b_out   = (const float*)d_in[5];
  float* out = (float*)d_out;   // reference output dtype is float32

  char* ws = (char*)d_ws;
  const size_t MB = 1024 * 1024;
  bf16* xb   = (bf16*)(ws);
  bf16* wqb  = (bf16*)(ws + 16 * MB);
  bf16* wob  = (bf16*)(ws + 40 * MB);
  bf16* q_ws = (bf16*)(ws + 48 * MB);
  bf16* k_ws = (bf16*)(ws + 64 * MB);
  bf16* v_t  = (bf16*)(ws + 80 * MB);
  bf16* attn = xb;   // xb dead after gemm_qkv_k; distinct from q_ws (no alias)

  cvt3_k<<<dim3(24576), 256, 0, stream>>>(x_f, xb, w_qkv_f, wqb, w_out_f, wob);

  gemm_qkv_k<<<dim3(48, 32), 256, 0, stream>>>(xb, wqb, b_qkv, q_ws, k_ws, v_t);
  attn_k<<<dim3(256), 512, 0, stream>>>(q_ws, k_ws, v_t, attn);
  gemm_out_k<<<dim3(16, 32), 256, 0, stream>>>(attn, wob, b_out, out);
}